// Round 2
// baseline (5634.932 us; speedup 1.0000x reference)
//
#include <hip/hip_runtime.h>

typedef unsigned int uint_t;

#define NN 50000
#define NE 400000

// ws layout (float offsets)
#define AGG_S 0
#define AGG_V 3200000      // NN*64
#define CNT_O 12800000     // AGG_V + NN*192
#define WOFF  12850000     // CNT_O + NN
// weight offsets relative to wgt = ws + WOFF
#define RW1   0
#define RB1   64
#define RW2   128
#define RB2   4224
#define RW3T  4288         // transposed (128,64)
#define RB3   12480
#define RL1S  12608        // (64,192) as-is
#define RL1V  24896        // (64,64) as-is
#define RL2ST 28992        // transposed (32,160)
#define RL2VT 34112        // transposed (32,96)
#define WTOT  37184

__device__ __forceinline__ float sigf(float x){
  return __builtin_amdgcn_rcpf(1.0f + __expf(-x));
}
__device__ __forceinline__ float siluf(float x){ return x * sigf(x); }

// ---- Copy all weights/biases fp32 -> ws (some transposed) ----
__global__ __launch_bounds__(256) void convert_weights(
    const float* __restrict__ w1, const float* __restrict__ b1,
    const float* __restrict__ w2, const float* __restrict__ b2,
    const float* __restrict__ w3, const float* __restrict__ b3,
    const float* __restrict__ l1s, const float* __restrict__ l1v,
    const float* __restrict__ l2s, const float* __restrict__ l2v,
    float* __restrict__ wgt)
{
  int i = blockIdx.x*256 + threadIdx.x;
  if (i < 64)        { wgt[RW1 + i] = w1[i]; return; }
  if (i < 128)       { int t=i-64;    wgt[RB1 + t] = b1[t]; return; }
  if (i < 4224)      { int t=i-128;   wgt[RW2 + t] = w2[t]; return; }
  if (i < 4288)      { int t=i-4224;  wgt[RB2 + t] = b2[t]; return; }
  if (i < 12480)     { int t=i-4288;  int j=t>>7, m=t&127;
                       wgt[RW3T + m*64 + j] = w3[t]; return; }
  if (i < 12608)     { int t=i-12480; wgt[RB3 + t] = b3[t]; return; }
  if (i < 24896)     { int t=i-12608; wgt[RL1S + t] = l1s[t]; return; }
  if (i < 28992)     { int t=i-24896; wgt[RL1V + t] = l1v[t]; return; }
  if (i < 34112)     { int t=i-28992; int r=t>>5, c=t&31;
                       wgt[RL2ST + c*160 + r] = l2s[t]; return; }
  if (i < 37184)     { int t=i-34112; int r=t>>5, c=t&31;
                       wgt[RL2VT + c*96 + r] = l2v[t]; return; }
}

// ---- Edge phase: MLP(norm) -> scal; tensor product; atomic scatter ----
__global__ __launch_bounds__(256) void edge_kernel(
    const float* __restrict__ ns, const float* __restrict__ nv,
    const float* __restrict__ sh, const float* __restrict__ nrm,
    const int* __restrict__ snd, const int* __restrict__ rcv,
    const float* __restrict__ wgt, float* __restrict__ agg)
{
  int e = blockIdx.x*256 + threadIdx.x;
  if (e >= NE) return;
  float x   = nrm[e];
  float4 shv = *(const float4*)(sh + 4*e);
  float y0  = shv.x;
  float y10 = shv.y;
  float y11 = shv.z;
  float y12 = shv.w;
  int s = snd[e], r = rcv[e];

  // h2 = silu(h1 @ W2 + b2), h1[k] = silu(x*w1[k]+b1[k])
  float h2[64];
  const float* b2p = wgt + RB2;
  #pragma unroll
  for (int j=0;j<64;j++) h2[j] = b2p[j];
  const float* w1p = wgt + RW1;
  const float* b1p = wgt + RB1;
  for (int k=0;k<64;k++){
    float h1k = siluf(fmaf(x, w1p[k], b1p[k]));
    const float* r2 = wgt + RW2 + k*64;
    #pragma unroll
    for (int j=0;j<64;j++) h2[j] = fmaf(h1k, r2[j], h2[j]);
  }
  #pragma unroll
  for (int j=0;j<64;j++) h2[j] = siluf(h2[j]);

  // sender scalars (32 fp32 = 8 x float4)
  float se[32];
  {
    const float4* sp = (const float4*)(ns + (size_t)s*32);
    #pragma unroll
    for (int q=0;q<8;q++){
      float4 v = sp[q];
      se[4*q+0]=v.x; se[4*q+1]=v.y; se[4*q+2]=v.z; se[4*q+3]=v.w;
    }
  }
  const float* vrow = nv + (size_t)s*96;
  float* aggS = agg + AGG_S + (size_t)r*64;
  float* aggV = agg + AGG_V + (size_t)r*192;
  const float* b3p = wgt + RB3;
  const float* w3t = wgt + RW3T;
  const float inv_sqrt3 = 0.57735026918962576f;

  #pragma unroll 4
  for (int m=0;m<32;m++){
    // scal rows m, 32+m, 64+m, 96+m via transposed w3
    float s0=b3p[m], s1=b3p[32+m], s2=b3p[64+m], s3=b3p[96+m];
    const float* t0 = w3t + m*64;
    const float* t1 = w3t + (32+m)*64;
    const float* t2 = w3t + (64+m)*64;
    const float* t3 = w3t + (96+m)*64;
    #pragma unroll
    for (int j=0;j<64;j++){
      float h = h2[j];
      s0 = fmaf(h, t0[j], s0);
      s1 = fmaf(h, t1[j], s1);
      s2 = fmaf(h, t2[j], s2);
      s3 = fmaf(h, t3[j], s3);
    }
    float v0 = vrow[3*m+0];
    float v1 = vrow[3*m+1];
    float v2 = vrow[3*m+2];
    float sem = se[m];
    // tp_s[m] = y0*s_e[m]*scal[m]
    atomicAdd(aggS + m, y0*sem*s0);
    // tp_s[32+m] = dot(y1, v_e[m])/sqrt(3)*scal[32+m]
    float dot = fmaf(y12, v2, fmaf(y11, v1, y10*v0));
    atomicAdd(aggS + 32 + m, dot*inv_sqrt3*s1);
    // tp_v[m][k] = y0*v_e[m][k]*scal[64+m]
    float c2 = y0*s2;
    atomicAdd(aggV + 3*m+0, c2*v0);
    atomicAdd(aggV + 3*m+1, c2*v1);
    atomicAdd(aggV + 3*m+2, c2*v2);
    // tp_v[32+m][k] = y1[k]*s_e[m]*scal[96+m]
    float c3 = sem*s3;
    atomicAdd(aggV + 96 + 3*m+0, y10*c3);
    atomicAdd(aggV + 96 + 3*m+1, y11*c3);
    atomicAdd(aggV + 96 + 3*m+2, y12*c3);
  }
  atomicAdd(agg + CNT_O + r, 1.0f);
}

// ---- Node phase: 4 wave-uniform roles per 64-node chunk ----
__global__ __launch_bounds__(256) void node_kernel(
    const float* __restrict__ ns, const float* __restrict__ nv,
    const float* __restrict__ wgt, const float* __restrict__ agg,
    float* __restrict__ out)
{
  int lane = threadIdx.x & 63;
  int role = threadIdx.x >> 6;
  int n = blockIdx.x*64 + lane;
  if (n >= NN) return;
  float inv_den = __builtin_amdgcn_rcpf(fmaxf(agg[CNT_O + n], 1.0f));
  const float* aggS = agg + AGG_S + (size_t)n*64;

  if (role == 0){
    // x_s[:,0:128] -> act_s -> o_s
    float acc[128];
    #pragma unroll
    for (int o=0;o<128;o++) acc[o]=0.0f;
    for (int m=0;m<64;m++){
      float a = aggS[m]*inv_den;
      const float* row = wgt + RL1S + m*192;
      #pragma unroll
      for (int o=0;o<128;o++) acc[o] = fmaf(a, row[o], acc[o]);
    }
    #pragma unroll
    for (int o=0;o<128;o++) acc[o] = siluf(acc[o]*0.125f);
    float nsr[32];
    {
      const float4* sp = (const float4*)(ns + (size_t)n*32);
      #pragma unroll
      for (int q=0;q<8;q++){
        float4 v = sp[q];
        nsr[4*q+0]=v.x; nsr[4*q+1]=v.y; nsr[4*q+2]=v.z; nsr[4*q+3]=v.w;
      }
    }
    float* op = out + (size_t)n*128;
    for (int j=0;j<32;j++){
      const float* rw = wgt + RL2ST + j*160;
      float a2 = 0.0f;
      #pragma unroll
      for (int i=0;i<128;i++) a2 = fmaf(acc[i], rw[i], a2);
      #pragma unroll
      for (int q=0;q<32;q++)  a2 = fmaf(nsr[q], rw[128+q], a2);
      op[j] = a2 * 0.07905694150420949f;   // 1/sqrt(160)
    }
  } else {
    int k = role - 1;
    // gates (x_s[:,128:192]) and x_v[:,k]
    float ga[64], xv[64];
    #pragma unroll
    for (int o=0;o<64;o++){ ga[o]=0.0f; xv[o]=0.0f; }
    for (int m=0;m<64;m++){
      float a = aggS[m]*inv_den;
      const float* row = wgt + RL1S + m*192 + 128;
      #pragma unroll
      for (int o=0;o<64;o++) ga[o] = fmaf(a, row[o], ga[o]);
    }
    const float* aggVn = agg + AGG_V + (size_t)n*192 + k;
    for (int m=0;m<64;m++){
      float av = aggVn[3*m]*inv_den;
      const float* row = wgt + RL1V + m*64;
      #pragma unroll
      for (int o=0;o<64;o++) xv[o] = fmaf(av, row[o], xv[o]);
    }
    #pragma unroll
    for (int o=0;o<64;o++) xv[o] = xv[o]*0.125f*sigf(ga[o]*0.125f);  // g_v[:,k]
    float nvr[32];
    #pragma unroll
    for (int q=0;q<32;q++) nvr[q] = nv[(size_t)n*96 + 3*q + k];
    float* op = out + (size_t)n*128 + 32 + k;
    for (int j=0;j<32;j++){
      const float* rw = wgt + RL2VT + j*96;
      float a2 = 0.0f;
      #pragma unroll
      for (int i=0;i<64;i++) a2 = fmaf(xv[i], rw[i], a2);
      #pragma unroll
      for (int q=0;q<32;q++) a2 = fmaf(nvr[q], rw[64+q], a2);
      op[3*j] = a2 * 0.10206207261596576f;  // 1/sqrt(96)
    }
  }
}

extern "C" void kernel_launch(void* const* d_in, const int* in_sizes, int n_in,
                              void* d_out, int out_size, void* d_ws, size_t ws_size,
                              hipStream_t stream) {
  const float* node_scalars = (const float*)d_in[0];
  const float* node_vectors = (const float*)d_in[1];
  const float* sh           = (const float*)d_in[2];
  const float* norm         = (const float*)d_in[3];
  const float* w1  = (const float*)d_in[4];
  const float* b1  = (const float*)d_in[5];
  const float* w2  = (const float*)d_in[6];
  const float* b2  = (const float*)d_in[7];
  const float* w3  = (const float*)d_in[8];
  const float* b3  = (const float*)d_in[9];
  const float* l1s = (const float*)d_in[10];
  const float* l1v = (const float*)d_in[11];
  const float* l2s = (const float*)d_in[12];
  const float* l2v = (const float*)d_in[13];
  const int* snd = (const int*)d_in[14];
  const int* rcv = (const int*)d_in[15];
  float* ws = (float*)d_ws;
  float* out = (float*)d_out;

  if (ws_size < (size_t)(WOFF + WTOT) * 4) return;  // need ~51.6 MB scratch

  // zero agg_s/agg_v/cnt (ws is re-poisoned before every launch)
  hipMemsetAsync(d_ws, 0, (size_t)WOFF * 4, stream);

  convert_weights<<<(WTOT+255)/256, 256, 0, stream>>>(
      w1,b1,w2,b2,w3,b3,l1s,l1v,l2s,l2v, ws + WOFF);

  edge_kernel<<<(NE+255)/256, 256, 0, stream>>>(
      node_scalars, node_vectors, sh, norm, snd, rcv, ws + WOFF, ws);

  node_kernel<<<(NN+63)/64, 256, 0, stream>>>(
      node_scalars, node_vectors, ws + WOFF, ws, out);
}

// Round 3
// 5591.649 us; speedup vs baseline: 1.0077x; 1.0077x over previous
//
#include <hip/hip_runtime.h>

typedef unsigned int uint_t;

#define NN 50000
#define NE 400000

// ---------- NEW-path ws layout (float offsets) ----------
#define TP_OFF   0ull            // NE*256 = 102,400,000 floats
#define AGG_OFF  102400000ull    // NN*256 =  12,800,000 floats
#define WGT_OFF  115200000ull    // 37,184 floats
#define I_OFF    115240000ull    // int region (cast to int*)
// int offsets inside int region
#define ICNT  0
#define IOFFS NN                 // NN+1 entries
#define ICURS (2*NN+1)
#define IEIDS (3*NN+1)
#define N_INTS (3*NN+1+NE)       // 550,001
#define NEW_WS_BYTES ((I_OFF + (unsigned long long)N_INTS) * 4ull)

// ---------- Fallback (atomic) ws layout ----------
#define F_AGG 0ull               // NN*256
#define F_CNT 12800000ull        // NN floats
#define F_WGT 12850000ull
#define F_WS_BYTES ((12850000ull + 37184ull) * 4ull)

// weight offsets relative to wgt base
#define RW1   0
#define RB1   64
#define RW2   128
#define RB2   4224
#define RW3T  4288         // transposed (128,64)
#define RB3   12480
#define RL1S  12608        // (64,192) as-is
#define RL1V  24896        // (64,64) as-is
#define RL2ST 28992        // transposed (32,160)
#define RL2VT 34112        // transposed (32,96)
#define WTOT  37184
#define EDGE_W 12608       // floats staged in LDS by edge kernel (w1,b1,w2,b2,w3t,b3)

__device__ __forceinline__ float sigf(float x){
  return __builtin_amdgcn_rcpf(1.0f + __expf(-x));
}
__device__ __forceinline__ float siluf(float x){ return x * sigf(x); }

// ---- Copy all weights/biases fp32 -> ws (some transposed) ----
__global__ __launch_bounds__(256) void convert_weights(
    const float* __restrict__ w1, const float* __restrict__ b1,
    const float* __restrict__ w2, const float* __restrict__ b2,
    const float* __restrict__ w3, const float* __restrict__ b3,
    const float* __restrict__ l1s, const float* __restrict__ l1v,
    const float* __restrict__ l2s, const float* __restrict__ l2v,
    float* __restrict__ wgt)
{
  int i = blockIdx.x*256 + threadIdx.x;
  if (i < 64)        { wgt[RW1 + i] = w1[i]; return; }
  if (i < 128)       { int t=i-64;    wgt[RB1 + t] = b1[t]; return; }
  if (i < 4224)      { int t=i-128;   wgt[RW2 + t] = w2[t]; return; }
  if (i < 4288)      { int t=i-4224;  wgt[RB2 + t] = b2[t]; return; }
  if (i < 12480)     { int t=i-4288;  int j=t>>7, m=t&127;
                       wgt[RW3T + m*64 + j] = w3[t]; return; }
  if (i < 12608)     { int t=i-12480; wgt[RB3 + t] = b3[t]; return; }
  if (i < 24896)     { int t=i-12608; wgt[RL1S + t] = l1s[t]; return; }
  if (i < 28992)     { int t=i-24896; wgt[RL1V + t] = l1v[t]; return; }
  if (i < 34112)     { int t=i-28992; int r=t>>5, c=t&31;
                       wgt[RL2ST + c*160 + r] = l2s[t]; return; }
  if (i < 37184)     { int t=i-34112; int r=t>>5, c=t&31;
                       wgt[RL2VT + c*96 + r] = l2v[t]; return; }
}

// ================= CSR build =================
__global__ __launch_bounds__(256) void count_kernel(
    const int* __restrict__ rcv, int* __restrict__ cnt)
{
  int e = blockIdx.x*256 + threadIdx.x;
  if (e < NE) atomicAdd(&cnt[rcv[e]], 1);
}

__global__ __launch_bounds__(1024) void scan_kernel(
    const int* __restrict__ cnt, int* __restrict__ offs, int* __restrict__ curs)
{
  __shared__ int sdata[1024];
  int tid = threadIdx.x;
  const int CH = 49;               // 49*1024 = 50176 >= NN
  int base = tid*CH;
  int s = 0;
  for (int i=0;i<CH;i++){ int idx=base+i; if (idx<NN) s += cnt[idx]; }
  sdata[tid] = s;
  __syncthreads();
  // inclusive Hillis-Steele scan
  for (int off=1; off<1024; off<<=1){
    int t = 0;
    if (tid >= off) t = sdata[tid-off];
    __syncthreads();
    sdata[tid] += t;
    __syncthreads();
  }
  int run = sdata[tid] - s;        // exclusive prefix of this chunk
  for (int i=0;i<CH;i++){
    int idx = base+i;
    if (idx < NN){ offs[idx]=run; curs[idx]=run; run += cnt[idx]; }
  }
  if (tid == 1023) offs[NN] = run; // == NE
}

__global__ __launch_bounds__(256) void scatter_kernel(
    const int* __restrict__ rcv, int* __restrict__ curs, int* __restrict__ eids)
{
  int e = blockIdx.x*256 + threadIdx.x;
  if (e >= NE) return;
  int pos = atomicAdd(&curs[rcv[e]], 1);
  eids[pos] = e;
}

// ================= Edge phase (no atomics): MLP -> scal -> tp row =================
// tp row layout: 32 groups of 8: [m][{tp_s(m), tp_s(32+m), tp_v(m,0..2), tp_v(32+m,0..2)}]
__global__ __launch_bounds__(256) void edge_tp_kernel(
    const float* __restrict__ ns, const float* __restrict__ nv,
    const float* __restrict__ sh, const float* __restrict__ nrm,
    const int* __restrict__ snd,
    const float* __restrict__ wgt, float* __restrict__ tp)
{
  __shared__ float smem[EDGE_W];
  for (int i=threadIdx.x; i<EDGE_W; i+=256) smem[i] = wgt[i];
  __syncthreads();
  int e = blockIdx.x*256 + threadIdx.x;
  if (e >= NE) return;

  const float* sw1  = smem + RW1;
  const float* sb1  = smem + RB1;
  const float* sw2  = smem + RW2;
  const float* sb2  = smem + RB2;
  const float* sw3t = smem + RW3T;
  const float* sb3  = smem + RB3;

  float x   = nrm[e];
  float4 shv = *(const float4*)(sh + 4*e);
  float y0  = shv.x, y10 = shv.y, y11 = shv.z, y12 = shv.w;
  int s = snd[e];

  // h2 = silu(silu(x*w1+b1) @ W2 + b2)
  float h2[64];
  #pragma unroll
  for (int j=0;j<64;j++) h2[j] = sb2[j];
  for (int k=0;k<64;k++){
    float h1k = siluf(fmaf(x, sw1[k], sb1[k]));
    const float4* r2 = (const float4*)(sw2 + (k<<6));
    #pragma unroll
    for (int j=0;j<16;j++){
      float4 w = r2[j];
      h2[4*j+0] = fmaf(h1k, w.x, h2[4*j+0]);
      h2[4*j+1] = fmaf(h1k, w.y, h2[4*j+1]);
      h2[4*j+2] = fmaf(h1k, w.z, h2[4*j+2]);
      h2[4*j+3] = fmaf(h1k, w.w, h2[4*j+3]);
    }
  }
  #pragma unroll
  for (int j=0;j<64;j++) h2[j] = siluf(h2[j]);

  // sender features
  float se[32];
  {
    const float4* sp = (const float4*)(ns + (size_t)s*32);
    #pragma unroll
    for (int q=0;q<8;q++){
      float4 v = sp[q];
      se[4*q+0]=v.x; se[4*q+1]=v.y; se[4*q+2]=v.z; se[4*q+3]=v.w;
    }
  }
  const float* vrow = nv + (size_t)s*96;
  float* orow = tp + (size_t)e*256;
  const float inv_sqrt3 = 0.57735026918962576f;

  #pragma unroll 4
  for (int m=0;m<32;m++){
    float s0=sb3[m], s1=sb3[32+m], s2=sb3[64+m], s3=sb3[96+m];
    const float4* t0 = (const float4*)(sw3t + m*64);
    const float4* t1 = (const float4*)(sw3t + (32+m)*64);
    const float4* t2 = (const float4*)(sw3t + (64+m)*64);
    const float4* t3 = (const float4*)(sw3t + (96+m)*64);
    #pragma unroll
    for (int j=0;j<16;j++){
      float4 h; h.x=h2[4*j]; h.y=h2[4*j+1]; h.z=h2[4*j+2]; h.w=h2[4*j+3];
      float4 w0=t0[j], w1_=t1[j], w2_=t2[j], w3_=t3[j];
      s0 = fmaf(h.x,w0.x, fmaf(h.y,w0.y, fmaf(h.z,w0.z, fmaf(h.w,w0.w, s0))));
      s1 = fmaf(h.x,w1_.x,fmaf(h.y,w1_.y,fmaf(h.z,w1_.z,fmaf(h.w,w1_.w,s1))));
      s2 = fmaf(h.x,w2_.x,fmaf(h.y,w2_.y,fmaf(h.z,w2_.z,fmaf(h.w,w2_.w,s2))));
      s3 = fmaf(h.x,w3_.x,fmaf(h.y,w3_.y,fmaf(h.z,w3_.z,fmaf(h.w,w3_.w,s3))));
    }
    float v0 = vrow[3*m+0], v1 = vrow[3*m+1], v2 = vrow[3*m+2];
    float sem = se[m];
    float dot = fmaf(y12, v2, fmaf(y11, v1, y10*v0));
    float c2 = y0*s2;
    float c3 = sem*s3;
    float4 o0, o1;
    o0.x = y0*sem*s0;
    o0.y = dot*inv_sqrt3*s1;
    o0.z = c2*v0;
    o0.w = c2*v1;
    o1.x = c2*v2;
    o1.y = y10*c3;
    o1.z = y11*c3;
    o1.w = y12*c3;
    *(float4*)(orow + m*8)     = o0;
    *(float4*)(orow + m*8 + 4) = o1;
  }
}

// ================= Gather: sum tp rows per node, divide, write agg =================
__global__ __launch_bounds__(256) void gather_kernel(
    const float* __restrict__ tp, const int* __restrict__ offs,
    const int* __restrict__ eids, float* __restrict__ agg)
{
  int n = blockIdx.x;
  int c = threadIdx.x;
  int s = offs[n], e2 = offs[n+1];
  float acc = 0.0f;
  for (int j=s; j<e2; j++){
    int eid = eids[j];
    acc += tp[(size_t)eid*256 + c];
  }
  int deg = e2 - s;
  float inv = __builtin_amdgcn_rcpf((float)(deg > 0 ? deg : 1));
  int m = c>>3, q = c&7;
  int idx;
  if (q==0)      idx = m;
  else if (q==1) idx = 32+m;
  else if (q<5)  idx = 64 + 3*m + (q-2);
  else           idx = 160 + 3*m + (q-5);
  agg[(size_t)n*256 + idx] = acc * inv;
}

// ================= Fallback edge kernel (atomics, new agg layout) =================
__global__ __launch_bounds__(256) void edge_atomic_kernel(
    const float* __restrict__ ns, const float* __restrict__ nv,
    const float* __restrict__ sh, const float* __restrict__ nrm,
    const int* __restrict__ snd, const int* __restrict__ rcv,
    const float* __restrict__ wgt, float* __restrict__ agg, float* __restrict__ cntf)
{
  int e = blockIdx.x*256 + threadIdx.x;
  if (e >= NE) return;
  float x   = nrm[e];
  float4 shv = *(const float4*)(sh + 4*e);
  float y0  = shv.x, y10 = shv.y, y11 = shv.z, y12 = shv.w;
  int s = snd[e], r = rcv[e];

  float h2[64];
  const float* b2p = wgt + RB2;
  #pragma unroll
  for (int j=0;j<64;j++) h2[j] = b2p[j];
  const float* w1p = wgt + RW1;
  const float* b1p = wgt + RB1;
  for (int k=0;k<64;k++){
    float h1k = siluf(fmaf(x, w1p[k], b1p[k]));
    const float* r2 = wgt + RW2 + k*64;
    #pragma unroll
    for (int j=0;j<64;j++) h2[j] = fmaf(h1k, r2[j], h2[j]);
  }
  #pragma unroll
  for (int j=0;j<64;j++) h2[j] = siluf(h2[j]);

  float se[32];
  {
    const float4* sp = (const float4*)(ns + (size_t)s*32);
    #pragma unroll
    for (int q=0;q<8;q++){
      float4 v = sp[q];
      se[4*q+0]=v.x; se[4*q+1]=v.y; se[4*q+2]=v.z; se[4*q+3]=v.w;
    }
  }
  const float* vrow = nv + (size_t)s*96;
  float* aggS = agg + (size_t)r*256;
  float* aggV = agg + (size_t)r*256 + 64;
  const float* b3p = wgt + RB3;
  const float* w3t = wgt + RW3T;
  const float inv_sqrt3 = 0.57735026918962576f;

  #pragma unroll 4
  for (int m=0;m<32;m++){
    float s0=b3p[m], s1=b3p[32+m], s2=b3p[64+m], s3=b3p[96+m];
    const float* t0 = w3t + m*64;
    const float* t1 = w3t + (32+m)*64;
    const float* t2 = w3t + (64+m)*64;
    const float* t3 = w3t + (96+m)*64;
    #pragma unroll
    for (int j=0;j<64;j++){
      float h = h2[j];
      s0 = fmaf(h, t0[j], s0);
      s1 = fmaf(h, t1[j], s1);
      s2 = fmaf(h, t2[j], s2);
      s3 = fmaf(h, t3[j], s3);
    }
    float v0 = vrow[3*m+0], v1 = vrow[3*m+1], v2 = vrow[3*m+2];
    float sem = se[m];
    atomicAdd(aggS + m, y0*sem*s0);
    float dot = fmaf(y12, v2, fmaf(y11, v1, y10*v0));
    atomicAdd(aggS + 32 + m, dot*inv_sqrt3*s1);
    float c2 = y0*s2;
    atomicAdd(aggV + 3*m+0, c2*v0);
    atomicAdd(aggV + 3*m+1, c2*v1);
    atomicAdd(aggV + 3*m+2, c2*v2);
    float c3 = sem*s3;
    atomicAdd(aggV + 96 + 3*m+0, y10*c3);
    atomicAdd(aggV + 96 + 3*m+1, y11*c3);
    atomicAdd(aggV + 96 + 3*m+2, y12*c3);
  }
  atomicAdd(cntf + r, 1.0f);
}

// ================= Node phase: 4 wave-uniform roles per 64-node chunk =================
__global__ __launch_bounds__(256) void node_kernel(
    const float* __restrict__ ns, const float* __restrict__ nv,
    const float* __restrict__ wgt, const float* __restrict__ agg,
    const float* __restrict__ cntf, int use_cnt,
    float* __restrict__ out)
{
  int lane = threadIdx.x & 63;
  int role = threadIdx.x >> 6;
  int n = blockIdx.x*64 + lane;
  if (n >= NN) return;
  float inv_den = 1.0f;
  if (use_cnt) inv_den = __builtin_amdgcn_rcpf(fmaxf(cntf[n], 1.0f));
  const float* aggS = agg + (size_t)n*256;
  const float* aggV = agg + (size_t)n*256 + 64;

  if (role == 0){
    float acc[128];
    #pragma unroll
    for (int o=0;o<128;o++) acc[o]=0.0f;
    for (int m=0;m<64;m++){
      float a = aggS[m]*inv_den;
      const float* row = wgt + RL1S + m*192;
      #pragma unroll
      for (int o=0;o<128;o++) acc[o] = fmaf(a, row[o], acc[o]);
    }
    #pragma unroll
    for (int o=0;o<128;o++) acc[o] = siluf(acc[o]*0.125f);
    float nsr[32];
    {
      const float4* sp = (const float4*)(ns + (size_t)n*32);
      #pragma unroll
      for (int q=0;q<8;q++){
        float4 v = sp[q];
        nsr[4*q+0]=v.x; nsr[4*q+1]=v.y; nsr[4*q+2]=v.z; nsr[4*q+3]=v.w;
      }
    }
    float* op = out + (size_t)n*128;
    for (int j=0;j<32;j++){
      const float* rw = wgt + RL2ST + j*160;
      float a2 = 0.0f;
      #pragma unroll
      for (int i=0;i<128;i++) a2 = fmaf(acc[i], rw[i], a2);
      #pragma unroll
      for (int q=0;q<32;q++)  a2 = fmaf(nsr[q], rw[128+q], a2);
      op[j] = a2 * 0.07905694150420949f;   // 1/sqrt(160)
    }
  } else {
    int k = role - 1;
    float ga[64], xv[64];
    #pragma unroll
    for (int o=0;o<64;o++){ ga[o]=0.0f; xv[o]=0.0f; }
    for (int m=0;m<64;m++){
      float a = aggS[m]*inv_den;
      const float* row = wgt + RL1S + m*192 + 128;
      #pragma unroll
      for (int o=0;o<64;o++) ga[o] = fmaf(a, row[o], ga[o]);
    }
    const float* aggVn = aggV + k;
    for (int m=0;m<64;m++){
      float av = aggVn[3*m]*inv_den;
      const float* row = wgt + RL1V + m*64;
      #pragma unroll
      for (int o=0;o<64;o++) xv[o] = fmaf(av, row[o], xv[o]);
    }
    #pragma unroll
    for (int o=0;o<64;o++) xv[o] = xv[o]*0.125f*sigf(ga[o]*0.125f);
    float nvr[32];
    #pragma unroll
    for (int q=0;q<32;q++) nvr[q] = nv[(size_t)n*96 + 3*q + k];
    float* op = out + (size_t)n*128 + 32 + k;
    for (int j=0;j<32;j++){
      const float* rw = wgt + RL2VT + j*96;
      float a2 = 0.0f;
      #pragma unroll
      for (int i=0;i<64;i++) a2 = fmaf(xv[i], rw[i], a2);
      #pragma unroll
      for (int q=0;q<32;q++) a2 = fmaf(nvr[q], rw[64+q], a2);
      op[3*j] = a2 * 0.10206207261596576f;  // 1/sqrt(96)
    }
  }
}

extern "C" void kernel_launch(void* const* d_in, const int* in_sizes, int n_in,
                              void* d_out, int out_size, void* d_ws, size_t ws_size,
                              hipStream_t stream) {
  const float* node_scalars = (const float*)d_in[0];
  const float* node_vectors = (const float*)d_in[1];
  const float* sh           = (const float*)d_in[2];
  const float* norm         = (const float*)d_in[3];
  const float* w1  = (const float*)d_in[4];
  const float* b1  = (const float*)d_in[5];
  const float* w2  = (const float*)d_in[6];
  const float* b2  = (const float*)d_in[7];
  const float* w3  = (const float*)d_in[8];
  const float* b3  = (const float*)d_in[9];
  const float* l1s = (const float*)d_in[10];
  const float* l1v = (const float*)d_in[11];
  const float* l2s = (const float*)d_in[12];
  const float* l2v = (const float*)d_in[13];
  const int* snd = (const int*)d_in[14];
  const int* rcv = (const int*)d_in[15];
  float* ws = (float*)d_ws;
  float* out = (float*)d_out;

  if (ws_size >= NEW_WS_BYTES) {
    // ---------- CSR + materialized-tp path ----------
    float* tp  = ws + TP_OFF;
    float* agg = ws + AGG_OFF;
    float* wgt = ws + WGT_OFF;
    int*   ib  = (int*)(ws + I_OFF);
    int* cnt  = ib + ICNT;
    int* offs = ib + IOFFS;
    int* curs = ib + ICURS;
    int* eids = ib + IEIDS;

    hipMemsetAsync(cnt, 0, NN*sizeof(int), stream);

    convert_weights<<<(WTOT+255)/256, 256, 0, stream>>>(
        w1,b1,w2,b2,w3,b3,l1s,l1v,l2s,l2v, wgt);

    count_kernel<<<(NE+255)/256, 256, 0, stream>>>(rcv, cnt);
    scan_kernel<<<1, 1024, 0, stream>>>(cnt, offs, curs);
    scatter_kernel<<<(NE+255)/256, 256, 0, stream>>>(rcv, curs, eids);

    edge_tp_kernel<<<(NE+255)/256, 256, 0, stream>>>(
        node_scalars, node_vectors, sh, norm, snd, wgt, tp);

    gather_kernel<<<NN, 256, 0, stream>>>(tp, offs, eids, agg);

    node_kernel<<<(NN+63)/64, 256, 0, stream>>>(
        node_scalars, node_vectors, wgt, agg, agg, 0, out);
  } else if (ws_size >= F_WS_BYTES) {
    // ---------- fallback: atomic path ----------
    float* agg  = ws + F_AGG;
    float* cntf = ws + F_CNT;
    float* wgt  = ws + F_WGT;

    hipMemsetAsync(ws, 0, (size_t)(F_CNT + NN) * 4, stream);

    convert_weights<<<(WTOT+255)/256, 256, 0, stream>>>(
        w1,b1,w2,b2,w3,b3,l1s,l1v,l2s,l2v, wgt);

    edge_atomic_kernel<<<(NE+255)/256, 256, 0, stream>>>(
        node_scalars, node_vectors, sh, norm, snd, rcv, wgt, agg, cntf);

    node_kernel<<<(NN+63)/64, 256, 0, stream>>>(
        node_scalars, node_vectors, wgt, agg, cntf, 1, out);
  }
}

// Round 4
// 1742.477 us; speedup vs baseline: 3.2339x; 3.2090x over previous
//
#include <hip/hip_runtime.h>

#define NN 50000
#define NE 400000
#define NCH 2
#define CNN 25000            // nodes per chunk
#define NB 16                // nodes per edge_agg block

// ---------- ws layout (float offsets) ----------
#define AGG_OFF 0ull                  // CNN*256 = 6,400,000 floats (reused per chunk)
#define WGT_OFF 6400000ull            // 37,184 floats
#define I_OFF   6438000ull            // int region
// int offsets inside int region
#define ICNT  0
#define IOFFS NN                      // NN+1 entries
#define ICURS (2*NN+1)
#define IEIDS (3*NN+1)
#define N_INTS (3*NN+1+NE)            // 550,001
#define WS_NEED ((I_OFF + (unsigned long long)N_INTS) * 4ull)   // ~28 MB

// weight offsets relative to wgt base
#define RW1   0
#define RB1   64
#define RW2   128
#define RB2   4224
#define RW3T  4288         // transposed (128,64)
#define RB3   12480
#define RL1S  12608        // (64,192) as-is
#define RL1V  24896        // (64,64) as-is
#define RL2ST 28992        // transposed (32,160)
#define RL2VT 34112        // transposed (32,96)
#define WTOT  37184
#define EDGE_W 12608       // floats staged in LDS (w1,b1,w2,b2,w3t,b3)

__device__ __forceinline__ float sigf(float x){
  return __builtin_amdgcn_rcpf(1.0f + __expf(-x));
}
__device__ __forceinline__ float siluf(float x){ return x * sigf(x); }

// ---- Copy all weights/biases fp32 -> ws (some transposed) ----
__global__ __launch_bounds__(256) void convert_weights(
    const float* __restrict__ w1, const float* __restrict__ b1,
    const float* __restrict__ w2, const float* __restrict__ b2,
    const float* __restrict__ w3, const float* __restrict__ b3,
    const float* __restrict__ l1s, const float* __restrict__ l1v,
    const float* __restrict__ l2s, const float* __restrict__ l2v,
    float* __restrict__ wgt)
{
  int i = blockIdx.x*256 + threadIdx.x;
  if (i < 64)        { wgt[RW1 + i] = w1[i]; return; }
  if (i < 128)       { int t=i-64;    wgt[RB1 + t] = b1[t]; return; }
  if (i < 4224)      { int t=i-128;   wgt[RW2 + t] = w2[t]; return; }
  if (i < 4288)      { int t=i-4224;  wgt[RB2 + t] = b2[t]; return; }
  if (i < 12480)     { int t=i-4288;  int j=t>>7, m=t&127;
                       wgt[RW3T + m*64 + j] = w3[t]; return; }
  if (i < 12608)     { int t=i-12480; wgt[RB3 + t] = b3[t]; return; }
  if (i < 24896)     { int t=i-12608; wgt[RL1S + t] = l1s[t]; return; }
  if (i < 28992)     { int t=i-24896; wgt[RL1V + t] = l1v[t]; return; }
  if (i < 34112)     { int t=i-28992; int r=t>>5, c=t&31;
                       wgt[RL2ST + c*160 + r] = l2s[t]; return; }
  if (i < 37184)     { int t=i-34112; int r=t>>5, c=t&31;
                       wgt[RL2VT + c*96 + r] = l2v[t]; return; }
}

// ================= CSR build =================
__global__ __launch_bounds__(256) void count_kernel(
    const int* __restrict__ rcv, int* __restrict__ cnt)
{
  int e = blockIdx.x*256 + threadIdx.x;
  if (e < NE) atomicAdd(&cnt[rcv[e]], 1);
}

__global__ __launch_bounds__(1024) void scan_kernel(
    const int* __restrict__ cnt, int* __restrict__ offs, int* __restrict__ curs)
{
  __shared__ int sdata[1024];
  int tid = threadIdx.x;
  const int CH = 49;               // 49*1024 = 50176 >= NN
  int base = tid*CH;
  int s = 0;
  for (int i=0;i<CH;i++){ int idx=base+i; if (idx<NN) s += cnt[idx]; }
  sdata[tid] = s;
  __syncthreads();
  for (int off=1; off<1024; off<<=1){
    int t = 0;
    if (tid >= off) t = sdata[tid-off];
    __syncthreads();
    sdata[tid] += t;
    __syncthreads();
  }
  int run = sdata[tid] - s;        // exclusive prefix of this chunk
  for (int i=0;i<CH;i++){
    int idx = base+i;
    if (idx < NN){ offs[idx]=run; curs[idx]=run; run += cnt[idx]; }
  }
  if (tid == 1023) offs[NN] = run; // == NE
}

__global__ __launch_bounds__(256) void scatter_kernel(
    const int* __restrict__ rcv, int* __restrict__ curs, int* __restrict__ eids)
{
  int e = blockIdx.x*256 + threadIdx.x;
  if (e >= NE) return;
  int pos = atomicAdd(&curs[rcv[e]], 1);
  eids[pos] = e;
}

// ================= Fused edge + aggregate (no global atomics) =================
// Block owns NB consecutive receiver nodes; accumulates tp into padded LDS via
// ds_add_f32; flushes mean to agg (node-major, 256 per node, grouped layout:
// c = m*8+q, q: {s(m), s(32+m), v(m,0..2), v(32+m,0..2)}), already /deg.
__global__ __launch_bounds__(256) void edge_agg_kernel(
    const float* __restrict__ ns, const float* __restrict__ nv,
    const float* __restrict__ sh, const float* __restrict__ nrm,
    const int* __restrict__ snd, const int* __restrict__ rcv,
    const float* __restrict__ wgt,
    const int* __restrict__ offs, const int* __restrict__ eids,
    float* __restrict__ agg, int cn0, int cnn)
{
  __shared__ float swgt[EDGE_W];       // 50.4 KB
  __shared__ float acc[NB*257];        // 16.4 KB, stride 257 breaks bank aliasing
  int tid = threadIdx.x;
  for (int i=tid; i<EDGE_W; i+=256) swgt[i] = wgt[i];
  for (int i=tid; i<NB*257; i+=256) acc[i] = 0.0f;
  int n0 = cn0 + blockIdx.x*NB;
  int nc = cn0 + cnn - n0; if (nc > NB) nc = NB;
  __syncthreads();

  const float* sw1  = swgt + RW1;
  const float* sb1  = swgt + RB1;
  const float* sw2  = swgt + RW2;
  const float* sb2  = swgt + RB2;
  const float* sw3t = swgt + RW3T;
  const float* sb3  = swgt + RB3;
  const float inv_sqrt3 = 0.57735026918962576f;

  int pstart = offs[n0];
  int pend   = offs[n0+nc];

  for (int p = pstart + tid; p < pend; p += 256){
    int e = eids[p];
    int r = rcv[e];
    float* accn = acc + (r - n0)*257;

    float x = nrm[e];
    float4 shv = *(const float4*)(sh + 4*e);
    float y0 = shv.x, y10 = shv.y, y11 = shv.z, y12 = shv.w;
    int s = snd[e];

    // h2 = silu(silu(x*w1+b1) @ W2 + b2)
    float h2[64];
    #pragma unroll
    for (int j=0;j<64;j++) h2[j] = sb2[j];
    for (int k=0;k<64;k++){
      float h1k = siluf(fmaf(x, sw1[k], sb1[k]));
      const float4* r2 = (const float4*)(sw2 + (k<<6));
      #pragma unroll
      for (int j=0;j<16;j++){
        float4 w = r2[j];
        h2[4*j+0] = fmaf(h1k, w.x, h2[4*j+0]);
        h2[4*j+1] = fmaf(h1k, w.y, h2[4*j+1]);
        h2[4*j+2] = fmaf(h1k, w.z, h2[4*j+2]);
        h2[4*j+3] = fmaf(h1k, w.w, h2[4*j+3]);
      }
    }
    #pragma unroll
    for (int j=0;j<64;j++) h2[j] = siluf(h2[j]);

    float se[32];
    {
      const float4* sp = (const float4*)(ns + (size_t)s*32);
      #pragma unroll
      for (int q=0;q<8;q++){
        float4 v = sp[q];
        se[4*q+0]=v.x; se[4*q+1]=v.y; se[4*q+2]=v.z; se[4*q+3]=v.w;
      }
    }
    const float* vrow = nv + (size_t)s*96;

    #pragma unroll 4
    for (int m=0;m<32;m++){
      float s0=sb3[m], s1=sb3[32+m], s2=sb3[64+m], s3=sb3[96+m];
      const float4* t0 = (const float4*)(sw3t + (m<<6));
      const float4* t1 = (const float4*)(sw3t + ((32+m)<<6));
      const float4* t2 = (const float4*)(sw3t + ((64+m)<<6));
      const float4* t3 = (const float4*)(sw3t + ((96+m)<<6));
      #pragma unroll
      for (int j=0;j<16;j++){
        float hx=h2[4*j], hy=h2[4*j+1], hz=h2[4*j+2], hw=h2[4*j+3];
        float4 w0=t0[j], w1_=t1[j], w2_=t2[j], w3_=t3[j];
        s0 = fmaf(hx,w0.x, fmaf(hy,w0.y, fmaf(hz,w0.z, fmaf(hw,w0.w, s0))));
        s1 = fmaf(hx,w1_.x,fmaf(hy,w1_.y,fmaf(hz,w1_.z,fmaf(hw,w1_.w,s1))));
        s2 = fmaf(hx,w2_.x,fmaf(hy,w2_.y,fmaf(hz,w2_.z,fmaf(hw,w2_.w,s2))));
        s3 = fmaf(hx,w3_.x,fmaf(hy,w3_.y,fmaf(hz,w3_.z,fmaf(hw,w3_.w,s3))));
      }
      float v0 = vrow[3*m+0], v1 = vrow[3*m+1], v2 = vrow[3*m+2];
      float sem = se[m];
      float dot = fmaf(y12, v2, fmaf(y11, v1, y10*v0));
      float c2 = y0*s2;
      float c3 = sem*s3;
      float* an = accn + (m<<3);
      atomicAdd(an+0, y0*sem*s0);
      atomicAdd(an+1, dot*inv_sqrt3*s1);
      atomicAdd(an+2, c2*v0);
      atomicAdd(an+3, c2*v1);
      atomicAdd(an+4, c2*v2);
      atomicAdd(an+5, y10*c3);
      atomicAdd(an+6, y11*c3);
      atomicAdd(an+7, y12*c3);
    }
  }
  __syncthreads();

  // flush: mean (divide by degree), node-major coalesced
  for (int i=tid; i<nc*256; i+=256){
    int nl = i>>8, c = i&255;
    int deg = offs[n0+nl+1] - offs[n0+nl];
    float inv = (deg > 0) ? __builtin_amdgcn_rcpf((float)deg) : 1.0f;
    agg[(size_t)(n0 - cn0 + nl)*256 + c] = acc[nl*257 + c] * inv;
  }
}

// ================= Node phase: LDS agg slab + 4 wave-uniform roles =================
__global__ __launch_bounds__(256) void node_kernel(
    const float* __restrict__ ns, const float* __restrict__ nv,
    const float* __restrict__ wgt, const float* __restrict__ agg,
    int cn0, int cnn, float* __restrict__ out)
{
  __shared__ float sagg[64*257];       // 65.8 KB
  int tid = threadIdx.x;
  int nb0 = blockIdx.x*64;             // within chunk
  int ncount = cnn - nb0; if (ncount > 64) ncount = 64;
  for (int i=tid; i<ncount*256; i+=256){
    int nl = i>>8, c = i&255;
    sagg[nl*257 + c] = agg[(size_t)(nb0+nl)*256 + c];
  }
  __syncthreads();

  int lane = tid & 63, role = tid >> 6;
  if (lane >= ncount) return;
  int n = cn0 + nb0 + lane;
  const float* sa = sagg + lane*257;   // grouped layout, bank-staggered

  if (role == 0){
    // aggS[m]: m<32 -> c=m*8 ; m>=32 -> c=(m-32)*8+1
    float acc[128];
    #pragma unroll
    for (int o=0;o<128;o++) acc[o]=0.0f;
    for (int m=0;m<32;m++){
      float a = sa[m*8];
      const float* row = wgt + RL1S + m*192;
      #pragma unroll
      for (int o=0;o<128;o++) acc[o] = fmaf(a, row[o], acc[o]);
    }
    for (int m=0;m<32;m++){
      float a = sa[m*8+1];
      const float* row = wgt + RL1S + (32+m)*192;
      #pragma unroll
      for (int o=0;o<128;o++) acc[o] = fmaf(a, row[o], acc[o]);
    }
    #pragma unroll
    for (int o=0;o<128;o++) acc[o] = siluf(acc[o]*0.125f);
    float nsr[32];
    {
      const float4* sp = (const float4*)(ns + (size_t)n*32);
      #pragma unroll
      for (int q=0;q<8;q++){
        float4 v = sp[q];
        nsr[4*q+0]=v.x; nsr[4*q+1]=v.y; nsr[4*q+2]=v.z; nsr[4*q+3]=v.w;
      }
    }
    float* op = out + (size_t)n*128;
    for (int j=0;j<32;j++){
      const float* rw = wgt + RL2ST + j*160;
      float a2 = 0.0f;
      #pragma unroll
      for (int i=0;i<128;i++) a2 = fmaf(acc[i], rw[i], a2);
      #pragma unroll
      for (int q=0;q<32;q++)  a2 = fmaf(nsr[q], rw[128+q], a2);
      op[j] = a2 * 0.07905694150420949f;   // 1/sqrt(160)
    }
  } else {
    int k = role - 1;
    // aggS[m] for gates; aggV[m][k]: m<32 -> c=m*8+2+k ; m>=32 -> c=(m-32)*8+5+k
    float ga[64], xv[64];
    #pragma unroll
    for (int o=0;o<64;o++){ ga[o]=0.0f; xv[o]=0.0f; }
    for (int m=0;m<32;m++){
      float a = sa[m*8];
      const float* row = wgt + RL1S + m*192 + 128;
      #pragma unroll
      for (int o=0;o<64;o++) ga[o] = fmaf(a, row[o], ga[o]);
    }
    for (int m=0;m<32;m++){
      float a = sa[m*8+1];
      const float* row = wgt + RL1S + (32+m)*192 + 128;
      #pragma unroll
      for (int o=0;o<64;o++) ga[o] = fmaf(a, row[o], ga[o]);
    }
    for (int m=0;m<32;m++){
      float av = sa[m*8+2+k];
      const float* row = wgt + RL1V + m*64;
      #pragma unroll
      for (int o=0;o<64;o++) xv[o] = fmaf(av, row[o], xv[o]);
    }
    for (int m=0;m<32;m++){
      float av = sa[m*8+5+k];
      const float* row = wgt + RL1V + (32+m)*64;
      #pragma unroll
      for (int o=0;o<64;o++) xv[o] = fmaf(av, row[o], xv[o]);
    }
    #pragma unroll
    for (int o=0;o<64;o++) xv[o] = xv[o]*0.125f*sigf(ga[o]*0.125f);  // g_v[:,k]
    float nvr[32];
    #pragma unroll
    for (int q=0;q<32;q++) nvr[q] = nv[(size_t)n*96 + 3*q + k];
    float* op = out + (size_t)n*128 + 32 + k;
    for (int j=0;j<32;j++){
      const float* rw = wgt + RL2VT + j*96;
      float a2 = 0.0f;
      #pragma unroll
      for (int i=0;i<64;i++) a2 = fmaf(xv[i], rw[i], a2);
      #pragma unroll
      for (int q=0;q<32;q++) a2 = fmaf(nvr[q], rw[64+q], a2);
      op[3*j] = a2 * 0.10206207261596576f;  // 1/sqrt(96)
    }
  }
}

extern "C" void kernel_launch(void* const* d_in, const int* in_sizes, int n_in,
                              void* d_out, int out_size, void* d_ws, size_t ws_size,
                              hipStream_t stream) {
  const float* node_scalars = (const float*)d_in[0];
  const float* node_vectors = (const float*)d_in[1];
  const float* sh           = (const float*)d_in[2];
  const float* norm         = (const float*)d_in[3];
  const float* w1  = (const float*)d_in[4];
  const float* b1  = (const float*)d_in[5];
  const float* w2  = (const float*)d_in[6];
  const float* b2  = (const float*)d_in[7];
  const float* w3  = (const float*)d_in[8];
  const float* b3  = (const float*)d_in[9];
  const float* l1s = (const float*)d_in[10];
  const float* l1v = (const float*)d_in[11];
  const float* l2s = (const float*)d_in[12];
  const float* l2v = (const float*)d_in[13];
  const int* snd = (const int*)d_in[14];
  const int* rcv = (const int*)d_in[15];
  float* ws = (float*)d_ws;
  float* out = (float*)d_out;

  if (ws_size < WS_NEED) return;   // ~28 MB needed; known floor is >51 MB

  float* agg = ws + AGG_OFF;
  float* wgt = ws + WGT_OFF;
  int*   ib  = (int*)(ws + I_OFF);
  int* cnt  = ib + ICNT;
  int* offs = ib + IOFFS;
  int* curs = ib + ICURS;
  int* eids = ib + IEIDS;

  hipMemsetAsync(cnt, 0, NN*sizeof(int), stream);

  convert_weights<<<(WTOT+255)/256, 256, 0, stream>>>(
      w1,b1,w2,b2,w3,b3,l1s,l1v,l2s,l2v, wgt);

  count_kernel<<<(NE+255)/256, 256, 0, stream>>>(rcv, cnt);
  scan_kernel<<<1, 1024, 0, stream>>>(cnt, offs, curs);
  scatter_kernel<<<(NE+255)/256, 256, 0, stream>>>(rcv, curs, eids);

  for (int ch = 0; ch < NCH; ch++){
    int cn0 = ch * CNN;
    edge_agg_kernel<<<(CNN+NB-1)/NB, 256, 0, stream>>>(
        node_scalars, node_vectors, sh, norm, snd, rcv, wgt,
        offs, eids, agg, cn0, CNN);
    node_kernel<<<(CNN+63)/64, 256, 0, stream>>>(
        node_scalars, node_vectors, wgt, agg, cn0, CNN, out);
  }
}

// Round 5
// 710.062 us; speedup vs baseline: 7.9358x; 2.4540x over previous
//
#include <hip/hip_runtime.h>

#define NN 50000
#define NE 400000
#define NCH 2
#define CNN 25000            // nodes per chunk
#define NBINS 2048

// ---------- ws layout (float offsets) ----------
#define AGG_OFF  0ull                 // CNN*256 = 6,400,000 (reused per chunk)
#define WGT_OFF  6400000ull           // 37,184
#define SLUT_OFF 6437184ull           // (NBINS+1)*256 = 524,544
#define EH_OFF   6961728ull           // esh: NE float4 = 1,600,000 floats
#define EX_OFF   8561728ull           // ex:  NE floats
#define EN_OFF   8961728ull           // esnd: NE ints
#define I_OFF    9361728ull           // cnt NN, offs NN+1, curs NN
#define ICNT  0
#define IOFFS NN
#define ICURS (2*NN+1)
#define N_INTS (3*NN+1)               // 150,001
#define WS_NEED ((I_OFF + (unsigned long long)N_INTS) * 4ull)   // ~38 MB

// weight offsets relative to wgt base (node-phase weights)
#define RL1S  12608        // (64,192) as-is
#define RL1V  24896        // (64,64) as-is
#define RL2ST 28992        // transposed (32,160)
#define RL2VT 34112        // transposed (32,96)
#define WTOT  37184

__device__ __forceinline__ float sigf(float x){
  return __builtin_amdgcn_rcpf(1.0f + __expf(-x));
}
__device__ __forceinline__ float siluf(float x){ return x * sigf(x); }

// ---- Copy node-phase weights fp32 -> ws (some transposed) ----
__global__ __launch_bounds__(256) void convert_weights(
    const float* __restrict__ l1s, const float* __restrict__ l1v,
    const float* __restrict__ l2s, const float* __restrict__ l2v,
    float* __restrict__ wgt)
{
  int i = blockIdx.x*256 + threadIdx.x;
  if (i < 12608) return;  // region reserved (unused)
  if (i < 24896)     { int t=i-12608; wgt[RL1S + t] = l1s[t]; return; }
  if (i < 28992)     { int t=i-24896; wgt[RL1V + t] = l1v[t]; return; }
  if (i < 34112)     { int t=i-28992; int r=t>>5, c=t&31;
                       wgt[RL2ST + c*160 + r] = l2s[t]; return; }
  if (i < 37184)     { int t=i-34112; int r=t>>5, c=t&31;
                       wgt[RL2VT + c*96 + r] = l2v[t]; return; }
}

// ---- Build SLUT[bin][256]: scal(x) at bin edges, component-remapped ----
// component c=m*8+q -> scal idx: q0->m, q1->32+m, q2..4->64+m, q5..7->96+m
__global__ __launch_bounds__(128) void build_lut(
    const float* __restrict__ w1, const float* __restrict__ b1,
    const float* __restrict__ w2, const float* __restrict__ b2,
    const float* __restrict__ w3, const float* __restrict__ b3,
    float* __restrict__ slut)
{
  __shared__ float h1[64], h2[64], scal[128];
  int bin = blockIdx.x;            // 0..NBINS
  float x = (float)bin / (float)NBINS;
  int t = threadIdx.x;
  if (t < 64) h1[t] = siluf(fmaf(x, w1[t], b1[t]));
  __syncthreads();
  if (t < 64){
    float a = b2[t];
    for (int k=0;k<64;k++) a = fmaf(h1[k], w2[k*64+t], a);
    h2[t] = siluf(a);
  }
  __syncthreads();
  {
    float a = b3[t];
    for (int k=0;k<64;k++) a = fmaf(h2[k], w3[k*128+t], a);
    scal[t] = a;
  }
  __syncthreads();
  for (int c=t; c<256; c+=128){
    int m=c>>3, q=c&7;
    int idx = (q==0)? m : (q==1)? (32+m) : (q<5)? (64+m) : (96+m);
    slut[(size_t)bin*256 + c] = scal[idx];
  }
}

// ================= CSR build =================
__global__ __launch_bounds__(256) void count_kernel(
    const int* __restrict__ rcv, int* __restrict__ cnt)
{
  int e = blockIdx.x*256 + threadIdx.x;
  if (e < NE) atomicAdd(&cnt[rcv[e]], 1);
}

__global__ __launch_bounds__(1024) void scan_kernel(
    const int* __restrict__ cnt, int* __restrict__ offs, int* __restrict__ curs)
{
  __shared__ int sdata[1024];
  int tid = threadIdx.x;
  const int CH = 49;               // 49*1024 = 50176 >= NN
  int base = tid*CH;
  int s = 0;
  for (int i=0;i<CH;i++){ int idx=base+i; if (idx<NN) s += cnt[idx]; }
  sdata[tid] = s;
  __syncthreads();
  for (int off=1; off<1024; off<<=1){
    int t = 0;
    if (tid >= off) t = sdata[tid-off];
    __syncthreads();
    sdata[tid] += t;
    __syncthreads();
  }
  int run = sdata[tid] - s;        // exclusive prefix of this chunk
  for (int i=0;i<CH;i++){
    int idx = base+i;
    if (idx < NN){ offs[idx]=run; curs[idx]=run; run += cnt[idx]; }
  }
  if (tid == 1023) offs[NN] = run; // == NE
}

// scatter + pre-gather edge data into CSR order
__global__ __launch_bounds__(256) void scatter_kernel(
    const int* __restrict__ rcv, const int* __restrict__ snd,
    const float* __restrict__ nrm, const float* __restrict__ sh,
    int* __restrict__ curs,
    int* __restrict__ esnd, float* __restrict__ ex, float4* __restrict__ esh)
{
  int e = blockIdx.x*256 + threadIdx.x;
  if (e >= NE) return;
  int pos = atomicAdd(&curs[rcv[e]], 1);
  esnd[pos] = snd[e];
  ex[pos]   = nrm[e];
  esh[pos]  = *(const float4*)(sh + 4*e);
}

// ================= Fused edge+aggregate: wave per node, lane per 4 comps ====
__global__ __launch_bounds__(256) void edge_agg_kernel(
    const float* __restrict__ ns, const float* __restrict__ nv,
    const float4* __restrict__ esh, const float* __restrict__ ex,
    const int* __restrict__ esnd,
    const int* __restrict__ offs, const float* __restrict__ slut,
    float* __restrict__ agg, int cn0, int cnn)
{
  int wave = threadIdx.x >> 6;
  int lane = threadIdx.x & 63;
  int nl = blockIdx.x*4 + wave;        // node local in chunk
  if (nl >= cnn) return;
  int n = cn0 + nl;
  int m = lane >> 1;
  int odd = lane & 1;
  int p0 = offs[n], p1 = offs[n+1];
  const float4* slut4 = (const float4*)slut;
  const float inv_sqrt3 = 0.57735026918962576f;
  float a0=0.f, a1=0.f, a2=0.f, a3=0.f;

  for (int p=p0; p<p1; p++){
    int s    = esnd[p];
    float x  = ex[p];
    float4 y = esh[p];
    float f = x * (float)NBINS;
    f = fminf(fmaxf(f, 0.0f), (float)NBINS - 0.001f);
    int bin = (int)f;
    float tt = f - (float)bin;
    float4 L0 = slut4[(size_t)bin*64 + lane];
    float4 L1 = slut4[(size_t)(bin+1)*64 + lane];
    float sc0 = fmaf(tt, L1.x-L0.x, L0.x);
    float sc1 = fmaf(tt, L1.y-L0.y, L0.y);
    float sc2 = fmaf(tt, L1.z-L0.z, L0.z);
    float sc3 = fmaf(tt, L1.w-L0.w, L0.w);

    float se = ns[(size_t)s*32 + m];
    const float* vp = nv + (size_t)s*96 + 3*m;
    float v0 = vp[0], v1 = vp[1], v2 = vp[2];

    float A0,A1,A2,A3;
    if (!odd){
      float dot = fmaf(y.w, v2, fmaf(y.z, v1, y.y*v0));
      A0 = y.x*se; A1 = dot*inv_sqrt3; A2 = y.x*v0; A3 = y.x*v1;
    } else {
      A0 = y.x*v2; A1 = y.y*se; A2 = y.z*se; A3 = y.w*se;
    }
    a0 = fmaf(A0, sc0, a0);
    a1 = fmaf(A1, sc1, a1);
    a2 = fmaf(A2, sc2, a2);
    a3 = fmaf(A3, sc3, a3);
  }
  int deg = p1 - p0;
  float inv = (deg > 0) ? __builtin_amdgcn_rcpf((float)deg) : 1.0f;
  float4 o; o.x=a0*inv; o.y=a1*inv; o.z=a2*inv; o.w=a3*inv;
  *(float4*)(agg + (size_t)nl*256 + 4*lane) = o;
}

// ================= Node phase: LDS agg slab + 4 wave-uniform roles =========
__global__ __launch_bounds__(256) void node_kernel(
    const float* __restrict__ ns, const float* __restrict__ nv,
    const float* __restrict__ wgt, const float* __restrict__ agg,
    int cn0, int cnn, float* __restrict__ out)
{
  __shared__ float sagg[64*257];       // 65.8 KB
  int tid = threadIdx.x;
  int nb0 = blockIdx.x*64;             // within chunk
  int ncount = cnn - nb0; if (ncount > 64) ncount = 64;
  for (int i=tid; i<ncount*256; i+=256){
    int nl = i>>8, c = i&255;
    sagg[nl*257 + c] = agg[(size_t)(nb0+nl)*256 + c];
  }
  __syncthreads();

  int lane = tid & 63, role = tid >> 6;
  if (lane >= ncount) return;
  int n = cn0 + nb0 + lane;
  const float* sa = sagg + lane*257;

  if (role == 0){
    float acc[128];
    #pragma unroll
    for (int o=0;o<128;o++) acc[o]=0.0f;
    for (int m=0;m<32;m++){
      float a = sa[m*8];
      const float* row = wgt + RL1S + m*192;
      #pragma unroll
      for (int o=0;o<128;o++) acc[o] = fmaf(a, row[o], acc[o]);
    }
    for (int m=0;m<32;m++){
      float a = sa[m*8+1];
      const float* row = wgt + RL1S + (32+m)*192;
      #pragma unroll
      for (int o=0;o<128;o++) acc[o] = fmaf(a, row[o], acc[o]);
    }
    #pragma unroll
    for (int o=0;o<128;o++) acc[o] = siluf(acc[o]*0.125f);
    float nsr[32];
    {
      const float4* sp = (const float4*)(ns + (size_t)n*32);
      #pragma unroll
      for (int q=0;q<8;q++){
        float4 v = sp[q];
        nsr[4*q+0]=v.x; nsr[4*q+1]=v.y; nsr[4*q+2]=v.z; nsr[4*q+3]=v.w;
      }
    }
    float* op = out + (size_t)n*128;
    for (int j=0;j<32;j++){
      const float* rw = wgt + RL2ST + j*160;
      float a2 = 0.0f;
      #pragma unroll
      for (int i=0;i<128;i++) a2 = fmaf(acc[i], rw[i], a2);
      #pragma unroll
      for (int q=0;q<32;q++)  a2 = fmaf(nsr[q], rw[128+q], a2);
      op[j] = a2 * 0.07905694150420949f;   // 1/sqrt(160)
    }
  } else {
    int k = role - 1;
    float ga[64], xv[64];
    #pragma unroll
    for (int o=0;o<64;o++){ ga[o]=0.0f; xv[o]=0.0f; }
    for (int m=0;m<32;m++){
      float a = sa[m*8];
      const float* row = wgt + RL1S + m*192 + 128;
      #pragma unroll
      for (int o=0;o<64;o++) ga[o] = fmaf(a, row[o], ga[o]);
    }
    for (int m=0;m<32;m++){
      float a = sa[m*8+1];
      const float* row = wgt + RL1S + (32+m)*192 + 128;
      #pragma unroll
      for (int o=0;o<64;o++) ga[o] = fmaf(a, row[o], ga[o]);
    }
    for (int m=0;m<32;m++){
      float av = sa[m*8+2+k];
      const float* row = wgt + RL1V + m*64;
      #pragma unroll
      for (int o=0;o<64;o++) xv[o] = fmaf(av, row[o], xv[o]);
    }
    for (int m=0;m<32;m++){
      float av = sa[m*8+5+k];
      const float* row = wgt + RL1V + (32+m)*64;
      #pragma unroll
      for (int o=0;o<64;o++) xv[o] = fmaf(av, row[o], xv[o]);
    }
    #pragma unroll
    for (int o=0;o<64;o++) xv[o] = xv[o]*0.125f*sigf(ga[o]*0.125f);
    float nvr[32];
    #pragma unroll
    for (int q=0;q<32;q++) nvr[q] = nv[(size_t)n*96 + 3*q + k];
    float* op = out + (size_t)n*128 + 32 + k;
    for (int j=0;j<32;j++){
      const float* rw = wgt + RL2VT + j*96;
      float a2 = 0.0f;
      #pragma unroll
      for (int i=0;i<64;i++) a2 = fmaf(xv[i], rw[i], a2);
      #pragma unroll
      for (int q=0;q<32;q++) a2 = fmaf(nvr[q], rw[64+q], a2);
      op[3*j] = a2 * 0.10206207261596576f;  // 1/sqrt(96)
    }
  }
}

extern "C" void kernel_launch(void* const* d_in, const int* in_sizes, int n_in,
                              void* d_out, int out_size, void* d_ws, size_t ws_size,
                              hipStream_t stream) {
  const float* node_scalars = (const float*)d_in[0];
  const float* node_vectors = (const float*)d_in[1];
  const float* sh           = (const float*)d_in[2];
  const float* norm         = (const float*)d_in[3];
  const float* w1  = (const float*)d_in[4];
  const float* b1  = (const float*)d_in[5];
  const float* w2  = (const float*)d_in[6];
  const float* b2  = (const float*)d_in[7];
  const float* w3  = (const float*)d_in[8];
  const float* b3  = (const float*)d_in[9];
  const float* l1s = (const float*)d_in[10];
  const float* l1v = (const float*)d_in[11];
  const float* l2s = (const float*)d_in[12];
  const float* l2v = (const float*)d_in[13];
  const int* snd = (const int*)d_in[14];
  const int* rcv = (const int*)d_in[15];
  float* ws = (float*)d_ws;
  float* out = (float*)d_out;

  if (ws_size < WS_NEED) return;   // ~38 MB needed; known floor is >51 MB

  float* agg  = ws + AGG_OFF;
  float* wgt  = ws + WGT_OFF;
  float* slut = ws + SLUT_OFF;
  float4* esh = (float4*)(ws + EH_OFF);
  float* ex   = ws + EX_OFF;
  int* esnd   = (int*)(ws + EN_OFF);
  int* ib     = (int*)(ws + I_OFF);
  int* cnt  = ib + ICNT;
  int* offs = ib + IOFFS;
  int* curs = ib + ICURS;

  hipMemsetAsync(cnt, 0, NN*sizeof(int), stream);

  convert_weights<<<(WTOT+255)/256, 256, 0, stream>>>(l1s, l1v, l2s, l2v, wgt);
  build_lut<<<NBINS+1, 128, 0, stream>>>(w1,b1,w2,b2,w3,b3, slut);

  count_kernel<<<(NE+255)/256, 256, 0, stream>>>(rcv, cnt);
  scan_kernel<<<1, 1024, 0, stream>>>(cnt, offs, curs);
  scatter_kernel<<<(NE+255)/256, 256, 0, stream>>>(
      rcv, snd, norm, sh, curs, esnd, ex, esh);

  for (int ch = 0; ch < NCH; ch++){
    int cn0 = ch * CNN;
    edge_agg_kernel<<<(CNN+3)/4, 256, 0, stream>>>(
        node_scalars, node_vectors, esh, ex, esnd, offs, slut, agg, cn0, CNN);
    node_kernel<<<(CNN+63)/64, 256, 0, stream>>>(
        node_scalars, node_vectors, wgt, agg, cn0, CNN, out);
  }
}

// Round 6
// 563.643 us; speedup vs baseline: 9.9973x; 1.2598x over previous
//
#include <hip/hip_runtime.h>

#define NN 50000
#define NE 400000
#define CNN 25000
#define NBINS 1024

// weight offsets (new layout)
#define RL1ST 0            // l1s transposed: (192,64), col-contiguous
#define RL1VT 12288        // l1v transposed: (64,64)
#define RL2S  16384        // l2s original (160,32)
#define RL2V  21504        // l2v original (96,32)
#define WTOT  24576

#define SLUT_N ((NBINS+1)*256)        // 262400
#define N_INTS (3*NN+1+NE)            // 550001

// full path: agg NN*256 | wgt | slut | ints  -> 54.55 MB
#define FULL_AGG_FL   ((size_t)NN*256)
#define FULL_TOT_FL   (FULL_AGG_FL + WTOT + SLUT_N + N_INTS)
#define WS_FULL_BYTES (FULL_TOT_FL*4ull)
// chunked path: agg CNN*256 | wgt | slut | ints -> 28.95 MB (known to fit)
#define CH_AGG_FL     ((size_t)CNN*256)
#define CH_TOT_FL     (CH_AGG_FL + WTOT + SLUT_N + N_INTS)
#define WS_CH_BYTES   (CH_TOT_FL*4ull)

#define S160 0.07905694150420949f
#define S96  0.10206207261596576f

__device__ __forceinline__ float sigf(float x){
  return __builtin_amdgcn_rcpf(1.0f + __expf(-x));
}
__device__ __forceinline__ float siluf(float x){ return x * sigf(x); }

// ---- weights: transpose l1s,l1v; copy l2s,l2v ----
__global__ __launch_bounds__(256) void convert_weights(
    const float* __restrict__ l1s, const float* __restrict__ l1v,
    const float* __restrict__ l2s, const float* __restrict__ l2v,
    float* __restrict__ wgt)
{
  int i = blockIdx.x*256 + threadIdx.x;
  if (i < 12288){ int o=i>>6, m=i&63; wgt[RL1ST + i] = l1s[m*192+o]; return; }
  if (i < 16384){ int t=i-12288; int o=t>>6, m=t&63; wgt[RL1VT + t] = l1v[m*64+o]; return; }
  if (i < 21504){ int t=i-16384; wgt[RL2S + t] = l2s[t]; return; }
  if (i < 24576){ int t=i-21504; wgt[RL2V + t] = l2v[t]; return; }
}

// ---- SLUT[bin][256]: scal(x) at bin edges, component-remapped ----
// c=m*8+q -> scal idx: q0->m, q1->32+m, q2..4->64+m, q5..7->96+m
__global__ __launch_bounds__(128) void build_lut(
    const float* __restrict__ w1, const float* __restrict__ b1,
    const float* __restrict__ w2, const float* __restrict__ b2,
    const float* __restrict__ w3, const float* __restrict__ b3,
    float* __restrict__ slut)
{
  __shared__ float h1[64], h2[64], scal[128];
  int bin = blockIdx.x;            // 0..NBINS
  float x = (float)bin / (float)NBINS;
  int t = threadIdx.x;
  if (t < 64) h1[t] = siluf(fmaf(x, w1[t], b1[t]));
  __syncthreads();
  if (t < 64){
    float a = b2[t];
    for (int k=0;k<64;k++) a = fmaf(h1[k], w2[k*64+t], a);
    h2[t] = siluf(a);
  }
  __syncthreads();
  {
    float a = b3[t];
    for (int k=0;k<64;k++) a = fmaf(h2[k], w3[k*128+t], a);
    scal[t] = a;
  }
  __syncthreads();
  for (int c=t; c<256; c+=128){
    int m=c>>3, q=c&7;
    int idx = (q==0)? m : (q==1)? (32+m) : (q<5)? (64+m) : (96+m);
    slut[(size_t)bin*256 + c] = scal[idx];
  }
}

// ================= CSR build =================
__global__ __launch_bounds__(256) void count_kernel(
    const int* __restrict__ rcv, int* __restrict__ cnt)
{
  int e = blockIdx.x*256 + threadIdx.x;
  if (e < NE) atomicAdd(&cnt[rcv[e]], 1);
}

__global__ __launch_bounds__(1024) void scan_kernel(
    const int* __restrict__ cnt, int* __restrict__ offs, int* __restrict__ curs)
{
  __shared__ int sdata[1024];
  int tid = threadIdx.x;
  const int CH = 49;
  int base = tid*CH;
  int s = 0;
  for (int i=0;i<CH;i++){ int idx=base+i; if (idx<NN) s += cnt[idx]; }
  sdata[tid] = s;
  __syncthreads();
  for (int off=1; off<1024; off<<=1){
    int t = 0;
    if (tid >= off) t = sdata[tid-off];
    __syncthreads();
    sdata[tid] += t;
    __syncthreads();
  }
  int run = sdata[tid] - s;
  for (int i=0;i<CH;i++){
    int idx = base+i;
    if (idx < NN){ offs[idx]=run; curs[idx]=run; run += cnt[idx]; }
  }
  if (tid == 1023) offs[NN] = run;
}

__global__ __launch_bounds__(256) void scatter_kernel(
    const int* __restrict__ rcv, int* __restrict__ curs, int* __restrict__ eids)
{
  int e = blockIdx.x*256 + threadIdx.x;
  if (e >= NE) return;
  int pos = atomicAdd(&curs[rcv[e]], 1);
  eids[pos] = e;
}

// ================= Edge+aggregate: wave per node, lane per 4 comps =========
__global__ __launch_bounds__(256) void edge_agg_kernel(
    const float* __restrict__ ns, const float* __restrict__ nv,
    const float* __restrict__ sh, const float* __restrict__ nrm,
    const int* __restrict__ snd,
    const int* __restrict__ offs, const int* __restrict__ eids,
    const float* __restrict__ slut,
    float* __restrict__ agg, int cn0, int cnn)
{
  int wave = threadIdx.x >> 6;
  int lane = threadIdx.x & 63;
  int nl = blockIdx.x*4 + wave;
  if (nl >= cnn) return;
  int n = cn0 + nl;
  int m = lane >> 1;
  int odd = lane & 1;
  int p0 = offs[n], p1 = offs[n+1];
  const float4* slut4 = (const float4*)slut;
  const float inv_sqrt3 = 0.57735026918962576f;
  float a0=0.f, a1=0.f, a2=0.f, a3=0.f;

  for (int p=p0; p<p1; p++){
    int e    = eids[p];
    int s    = snd[e];
    float x  = nrm[e];
    float4 y = *(const float4*)(sh + 4*e);
    float f = x * (float)NBINS;
    f = fminf(fmaxf(f, 0.0f), (float)NBINS - 0.001f);
    int bin = (int)f;
    float tt = f - (float)bin;
    float4 L0 = slut4[(size_t)bin*64 + lane];
    float4 L1 = slut4[(size_t)(bin+1)*64 + lane];
    float sc0 = fmaf(tt, L1.x-L0.x, L0.x);
    float sc1 = fmaf(tt, L1.y-L0.y, L0.y);
    float sc2 = fmaf(tt, L1.z-L0.z, L0.z);
    float sc3 = fmaf(tt, L1.w-L0.w, L0.w);

    float se = ns[(size_t)s*32 + m];
    const float* vp = nv + (size_t)s*96 + 3*m;
    float v0 = vp[0], v1 = vp[1], v2 = vp[2];

    float A0,A1,A2,A3;
    if (!odd){
      float dot = fmaf(y.w, v2, fmaf(y.z, v1, y.y*v0));
      A0 = y.x*se; A1 = dot*inv_sqrt3; A2 = y.x*v0; A3 = y.x*v1;
    } else {
      A0 = y.x*v2; A1 = y.y*se; A2 = y.z*se; A3 = y.w*se;
    }
    a0 = fmaf(A0, sc0, a0);
    a1 = fmaf(A1, sc1, a1);
    a2 = fmaf(A2, sc2, a2);
    a3 = fmaf(A3, sc3, a3);
  }
  int deg = p1 - p0;
  float inv = (deg > 0) ? __builtin_amdgcn_rcpf((float)deg) : 1.0f;
  float4 o; o.x=a0*inv; o.y=a1*inv; o.z=a2*inv; o.w=a3*inv;
  *(float4*)(agg + (size_t)nl*256 + 4*lane) = o;
}

// ================= Node phase v2: col-major, agg in registers ==============
// lane = node (64/block); role = wave. Phase A: each role computes 16 gate
// cols -> LDS. Phase B: role0 = act_s+o_s fused; roles 1..3 = x_v[k]+o_v[k].
__global__ __launch_bounds__(256,3) void node_kernel(
    const float* __restrict__ ns, const float* __restrict__ nv,
    const float* __restrict__ wgt, const float* __restrict__ agg,
    int cn0, int cnn, float* __restrict__ out)
{
  __shared__ float sgate[64*64];     // [col][lane] 16 KB
  int lane = threadIdx.x & 63, role = threadIdx.x >> 6;
  int nl = blockIdx.x*64 + lane;
  bool valid = (nl < cnn);
  int n = cn0 + nl;
  float aggs[64];

  if (valid){
    const float2* ar = (const float2*)(agg + (size_t)nl*256);
    #pragma unroll
    for (int g=0; g<32; g++){
      float2 v = ar[4*g];            // c = 8g, 8g+1
      aggs[g] = v.x; aggs[32+g] = v.y;
    }
    const float* l1sT = wgt + RL1ST;
    for (int t=0;t<16;t++){
      int o = role*16 + t;
      const float4* col = (const float4*)(l1sT + (size_t)(128+o)*64);
      float d0=0,d1=0,d2=0,d3=0;
      #pragma unroll
      for (int j=0;j<16;j++){
        float4 c = col[j];
        d0 = fmaf(aggs[4*j+0], c.x, d0);
        d1 = fmaf(aggs[4*j+1], c.y, d1);
        d2 = fmaf(aggs[4*j+2], c.z, d2);
        d3 = fmaf(aggs[4*j+3], c.w, d3);
      }
      sgate[o*64+lane] = sigf(((d0+d1)+(d2+d3))*0.125f);
    }
  }
  __syncthreads();
  if (!valid) return;

  if (role == 0){
    float oacc[32];
    #pragma unroll
    for (int j=0;j<32;j++) oacc[j]=0.0f;
    const float* l1sT = wgt + RL1ST;
    const float* l2s  = wgt + RL2S;
    for (int o=0;o<128;o++){
      const float4* col = (const float4*)(l1sT + (size_t)o*64);
      float d0=0,d1=0,d2=0,d3=0;
      #pragma unroll
      for (int j=0;j<16;j++){
        float4 c = col[j];
        d0 = fmaf(aggs[4*j+0], c.x, d0);
        d1 = fmaf(aggs[4*j+1], c.y, d1);
        d2 = fmaf(aggs[4*j+2], c.z, d2);
        d3 = fmaf(aggs[4*j+3], c.w, d3);
      }
      float act = siluf(((d0+d1)+(d2+d3))*0.125f);
      const float4* row = (const float4*)(l2s + (size_t)o*32);
      #pragma unroll
      for (int j=0;j<8;j++){
        float4 w = row[j];
        oacc[4*j+0] = fmaf(act, w.x, oacc[4*j+0]);
        oacc[4*j+1] = fmaf(act, w.y, oacc[4*j+1]);
        oacc[4*j+2] = fmaf(act, w.z, oacc[4*j+2]);
        oacc[4*j+3] = fmaf(act, w.w, oacc[4*j+3]);
      }
    }
    const float4* sp = (const float4*)(ns + (size_t)n*32);
    #pragma unroll
    for (int q4=0;q4<8;q4++){
      float4 v = sp[q4];
      float vv[4] = {v.x, v.y, v.z, v.w};
      #pragma unroll
      for (int u=0;u<4;u++){
        float a = vv[u];
        const float4* row = (const float4*)(l2s + (size_t)(128+q4*4+u)*32);
        #pragma unroll
        for (int j=0;j<8;j++){
          float4 w = row[j];
          oacc[4*j+0] = fmaf(a, w.x, oacc[4*j+0]);
          oacc[4*j+1] = fmaf(a, w.y, oacc[4*j+1]);
          oacc[4*j+2] = fmaf(a, w.z, oacc[4*j+2]);
          oacc[4*j+3] = fmaf(a, w.w, oacc[4*j+3]);
        }
      }
    }
    float4* op = (float4*)(out + (size_t)n*128);
    #pragma unroll
    for (int j=0;j<8;j++){
      float4 o4;
      o4.x = oacc[4*j+0]*S160; o4.y = oacc[4*j+1]*S160;
      o4.z = oacc[4*j+2]*S160; o4.w = oacc[4*j+3]*S160;
      op[j] = o4;
    }
  } else {
    int k = role - 1;
    float aggv[64];
    const float* arow = agg + (size_t)nl*256;
    #pragma unroll
    for (int g=0; g<32; g++){
      aggv[g]    = arow[8*g + 2 + k];
      aggv[32+g] = arow[8*g + 5 + k];
    }
    float oacc[32];
    #pragma unroll
    for (int j=0;j<32;j++) oacc[j]=0.0f;
    const float* l1vT = wgt + RL1VT;
    const float* l2v  = wgt + RL2V;
    for (int o=0;o<64;o++){
      const float4* col = (const float4*)(l1vT + (size_t)o*64);
      float d0=0,d1=0,d2=0,d3=0;
      #pragma unroll
      for (int j=0;j<16;j++){
        float4 c = col[j];
        d0 = fmaf(aggv[4*j+0], c.x, d0);
        d1 = fmaf(aggv[4*j+1], c.y, d1);
        d2 = fmaf(aggv[4*j+2], c.z, d2);
        d3 = fmaf(aggv[4*j+3], c.w, d3);
      }
      float gv = (((d0+d1)+(d2+d3))*0.125f) * sgate[o*64+lane];
      const float4* row = (const float4*)(l2v + (size_t)o*32);
      #pragma unroll
      for (int j=0;j<8;j++){
        float4 w = row[j];
        oacc[4*j+0] = fmaf(gv, w.x, oacc[4*j+0]);
        oacc[4*j+1] = fmaf(gv, w.y, oacc[4*j+1]);
        oacc[4*j+2] = fmaf(gv, w.z, oacc[4*j+2]);
        oacc[4*j+3] = fmaf(gv, w.w, oacc[4*j+3]);
      }
    }
    const float* vp = nv + (size_t)n*96 + k;
    #pragma unroll 8
    for (int q=0;q<32;q++){
      float a = vp[3*q];
      const float4* row = (const float4*)(l2v + (size_t)(64+q)*32);
      #pragma unroll
      for (int j=0;j<8;j++){
        float4 w = row[j];
        oacc[4*j+0] = fmaf(a, w.x, oacc[4*j+0]);
        oacc[4*j+1] = fmaf(a, w.y, oacc[4*j+1]);
        oacc[4*j+2] = fmaf(a, w.z, oacc[4*j+2]);
        oacc[4*j+3] = fmaf(a, w.w, oacc[4*j+3]);
      }
    }
    float* op = out + (size_t)n*128 + 32 + k;
    #pragma unroll
    for (int j=0;j<32;j++) op[3*j] = oacc[j]*S96;
  }
}

extern "C" void kernel_launch(void* const* d_in, const int* in_sizes, int n_in,
                              void* d_out, int out_size, void* d_ws, size_t ws_size,
                              hipStream_t stream) {
  const float* node_scalars = (const float*)d_in[0];
  const float* node_vectors = (const float*)d_in[1];
  const float* sh           = (const float*)d_in[2];
  const float* norm         = (const float*)d_in[3];
  const float* w1  = (const float*)d_in[4];
  const float* b1  = (const float*)d_in[5];
  const float* w2  = (const float*)d_in[6];
  const float* b2  = (const float*)d_in[7];
  const float* w3  = (const float*)d_in[8];
  const float* b3  = (const float*)d_in[9];
  const float* l1s = (const float*)d_in[10];
  const float* l1v = (const float*)d_in[11];
  const float* l2s = (const float*)d_in[12];
  const float* l2v = (const float*)d_in[13];
  const int* snd = (const int*)d_in[14];
  const int* rcv = (const int*)d_in[15];
  float* ws = (float*)d_ws;
  float* out = (float*)d_out;

  if (ws_size < WS_CH_BYTES) return;

  bool full = (ws_size >= WS_FULL_BYTES);
  size_t aggfl = full ? FULL_AGG_FL : CH_AGG_FL;
  float* agg  = ws;
  float* wgt  = ws + aggfl;
  float* slut = wgt + WTOT;
  int*   ib   = (int*)(slut + SLUT_N);
  int* cnt  = ib;
  int* offs = ib + NN;
  int* curs = ib + 2*NN + 1;
  int* eids = ib + 3*NN + 1;

  hipMemsetAsync(cnt, 0, NN*sizeof(int), stream);

  convert_weights<<<(WTOT+255)/256, 256, 0, stream>>>(l1s, l1v, l2s, l2v, wgt);
  build_lut<<<NBINS+1, 128, 0, stream>>>(w1,b1,w2,b2,w3,b3, slut);

  count_kernel<<<(NE+255)/256, 256, 0, stream>>>(rcv, cnt);
  scan_kernel<<<1, 1024, 0, stream>>>(cnt, offs, curs);
  scatter_kernel<<<(NE+255)/256, 256, 0, stream>>>(rcv, curs, eids);

  int nchunks = full ? 1 : 2;
  int csize   = full ? NN : CNN;
  for (int ch = 0; ch < nchunks; ch++){
    int cn0 = ch * csize;
    edge_agg_kernel<<<(csize+3)/4, 256, 0, stream>>>(
        node_scalars, node_vectors, sh, norm, snd, offs, eids, slut,
        agg, cn0, csize);
    node_kernel<<<(csize+63)/64, 256, 0, stream>>>(
        node_scalars, node_vectors, wgt, agg, cn0, csize, out);
  }
}